// Round 2
// baseline (96.024 us; speedup 1.0000x reference)
//
#include <hip/hip_runtime.h>
#include <hip/hip_bf16.h>
#include <math.h>

#define B_ROWS 4096
#define NTOT   8192
#define DDIM   256
#define NTILE  32              // 8192 / 256 row/col tiles
#define CSCALE 1.6986436f      // sqrt(2*log2(e)); zn scaled so A.B = 2*log2(e)*cos

typedef __attribute__((ext_vector_type(8))) short  short8;   // 8 bf16
typedef __attribute__((ext_vector_type(4))) float  f32x4;

static __device__ inline unsigned short f2bf(float x) {
    union { float f; unsigned u; } v; v.f = x;
    unsigned r = v.u + 0x7fffu + ((v.u >> 16) & 1u);  // RNE
    return (unsigned short)(r >> 16);
}

// ---- kernel 1: fused normalize (scaled bf16) + positive-pair sims + sumexp zeroing ----
// grid 1024 x 256thr; one wave per pair (i, i+B).
__global__ __launch_bounds__(256) void norm_kernel(
        const float* __restrict__ zi, const float* __restrict__ zj,
        unsigned short* __restrict__ zn, float* __restrict__ simpos,
        float* __restrict__ sumexp) {
    int pair = blockIdx.x * 4 + (threadIdx.x >> 6);
    int lane = threadIdx.x & 63;
    float4 vi = reinterpret_cast<const float4*>(zi + (size_t)pair * DDIM)[lane];
    float4 vj = reinterpret_cast<const float4*>(zj + (size_t)pair * DDIM)[lane];
    float ssi = vi.x*vi.x + vi.y*vi.y + vi.z*vi.z + vi.w*vi.w;
    float ssj = vj.x*vj.x + vj.y*vj.y + vj.z*vj.z + vj.w*vj.w;
    float dij = vi.x*vj.x + vi.y*vj.y + vi.z*vj.z + vi.w*vj.w;
    #pragma unroll
    for (int o = 32; o > 0; o >>= 1) {
        ssi += __shfl_xor(ssi, o);
        ssj += __shfl_xor(ssj, o);
        dij += __shfl_xor(dij, o);
    }
    float invi = 1.0f / fmaxf(sqrtf(ssi), 1e-8f);
    float invj = 1.0f / fmaxf(sqrtf(ssj), 1e-8f);
    float si = CSCALE * invi, sj = CSCALE * invj;
    ushort4 hi4, hj4;
    hi4.x = f2bf(vi.x * si); hi4.y = f2bf(vi.y * si);
    hi4.z = f2bf(vi.z * si); hi4.w = f2bf(vi.w * si);
    hj4.x = f2bf(vj.x * sj); hj4.y = f2bf(vj.y * sj);
    hj4.z = f2bf(vj.z * sj); hj4.w = f2bf(vj.w * sj);
    *reinterpret_cast<ushort4*>(zn + (size_t)pair * DDIM + lane * 4) = hi4;
    *reinterpret_cast<ushort4*>(zn + (size_t)(pair + B_ROWS) * DDIM + lane * 4) = hj4;
    if (lane == 0) simpos[pair] = 2.0f * dij * invi * invj;   // logits = cos/tau = 2*cos
    if (threadIdx.x < 8) sumexp[blockIdx.x * 8 + threadIdx.x] = 0.0f;  // zero 8192 accs
}

// ---- kernel 2: triangular fused sim + exp2 + row/col exp-sums ----
// 2112 blocks = 528 upper-tri (ti,tj) tiles x 4 col-quarters.
// Block = 256 rows (4 waves x 64 rows in regs) x 64 cols (LDS-staged).
template<bool DIAG>
__device__ __forceinline__ void sim_body(
        const unsigned short* __restrict__ zn, float* __restrict__ sumexp,
        int rowBase, int colBase, unsigned char* tile) {
    int lane = threadIdx.x & 63;
    int l15 = lane & 15;
    int l4  = lane >> 4;

    // A fragments: 64 rows per wave held in registers (128 VGPRs)
    short8 a[4][8];
    #pragma unroll
    for (int rs = 0; rs < 4; ++rs) {
        const unsigned short* ap = zn + (size_t)(rowBase + rs * 16 + l15) * DDIM;
        #pragma unroll
        for (int c = 0; c < 8; ++c)
            a[rs][c] = *reinterpret_cast<const short8*>(ap + c * 32 + l4 * 8);
    }

    // stage 64 cols x 256 k bf16 = 32 KB, XOR-swizzled
    #pragma unroll
    for (int p = 0; p < 8; ++p) {
        int id = p * 256 + threadIdx.x;
        int tr = id >> 5, ck = id & 31;
        uint4 v = *reinterpret_cast<const uint4*>(
            zn + (size_t)(colBase + tr) * DDIM + ck * 8);
        int off = tr * 512 + ((ck * 16) ^ ((tr & 7) << 4));
        *reinterpret_cast<uint4*>(tile + off) = v;
    }
    __syncthreads();

    float rsum[4][4] = {{0,0,0,0},{0,0,0,0},{0,0,0,0},{0,0,0,0}};
    float csum[4];

    #pragma unroll
    for (int sub = 0; sub < 4; ++sub) {
        short8 b[8];
        int trr = sub * 16 + l15;
        int rowoff = trr * 512, swz = (trr & 7) << 4;
        #pragma unroll
        for (int c = 0; c < 8; ++c)
            b[c] = *reinterpret_cast<const short8*>(tile + rowoff + ((c * 64 + l4 * 16) ^ swz));
        int gcol = colBase + sub * 16 + l15;
        float cs = 0.0f;
        #pragma unroll
        for (int rs = 0; rs < 4; ++rs) {
            f32x4 acc = {0.f, 0.f, 0.f, 0.f};
            #pragma unroll
            for (int c = 0; c < 8; ++c)
                acc = __builtin_amdgcn_mfma_f32_16x16x32_bf16(a[rs][c], b[c], acc, 0, 0, 0);
            #pragma unroll
            for (int j = 0; j < 4; ++j) {
                float e = exp2f(acc[j]);         // zn pre-scaled: acc = 2*log2e*cos
                if (DIAG) {
                    int grow = rowBase + rs * 16 + l4 * 4 + j;
                    e = (grow == gcol) ? 0.0f : e;   // mask self-similarity
                }
                rsum[rs][j] += e;
                cs += e;
            }
        }
        csum[sub] = cs;
    }

    // row sums: reduce across the 16 col-lanes
    #pragma unroll
    for (int rs = 0; rs < 4; ++rs)
        #pragma unroll
        for (int j = 0; j < 4; ++j) {
            float s = rsum[rs][j];
            #pragma unroll
            for (int m = 8; m >= 1; m >>= 1) s += __shfl_xor(s, m);
            rsum[rs][j] = s;
        }
    if (l15 == 0) {
        #pragma unroll
        for (int rs = 0; rs < 4; ++rs)
            #pragma unroll
            for (int j = 0; j < 4; ++j)
                atomicAdd(&sumexp[rowBase + rs * 16 + l4 * 4 + j], rsum[rs][j]);
    }
    // col sums (transposed contribution), skip for diagonal tiles
    if (!DIAG) {
        #pragma unroll
        for (int sub = 0; sub < 4; ++sub) {
            float s = csum[sub];
            s += __shfl_xor(s, 16);
            s += __shfl_xor(s, 32);
            if (l4 == 0) atomicAdd(&sumexp[colBase + sub * 16 + l15], s);
        }
    }
}

__global__ __launch_bounds__(256, 2) void sim_kernel(
        const unsigned short* __restrict__ zn, float* __restrict__ sumexp) {
    __shared__ __align__(16) unsigned char tile[64 * 512];  // 32 KB
    int pairIdx = blockIdx.x >> 2, q = blockIdx.x & 3;
    int ti = 0, rem = pairIdx;
    while (rem >= NTILE - ti) { rem -= NTILE - ti; ++ti; }   // uniform decode
    int tj = ti + rem;
    int wid = threadIdx.x >> 6;
    int rowBase = ti * 256 + wid * 64;
    int colBase = tj * 256 + q * 64;
    if (ti == tj) sim_body<true >(zn, sumexp, rowBase, colBase, tile);
    else          sim_body<false>(zn, sumexp, rowBase, colBase, tile);
}

// ---- kernel 3: loss = sum_r (log(sumexp[r]) - simpos[r % B]) / N ----
__global__ __launch_bounds__(256) void finalize_kernel(
        const float* __restrict__ sumexp, const float* __restrict__ simpos,
        float* __restrict__ out) {
    __shared__ float red[4];
    float acc = 0.0f;
    for (int r = threadIdx.x; r < NTOT; r += 256)
        acc += logf(sumexp[r]) - simpos[r & (B_ROWS - 1)];
    #pragma unroll
    for (int o = 32; o > 0; o >>= 1) acc += __shfl_xor(acc, o);
    if ((threadIdx.x & 63) == 0) red[threadIdx.x >> 6] = acc;
    __syncthreads();
    if (threadIdx.x == 0)
        out[0] = (red[0] + red[1] + red[2] + red[3]) / (float)NTOT;
}

extern "C" void kernel_launch(void* const* d_in, const int* in_sizes, int n_in,
                              void* d_out, int out_size, void* d_ws, size_t ws_size,
                              hipStream_t stream) {
    const float* zi = (const float*)d_in[0];
    const float* zj = (const float*)d_in[1];
    float* out = (float*)d_out;

    unsigned short* zn = (unsigned short*)d_ws;                       // 4 MB
    float* sumexp = (float*)((char*)d_ws + (size_t)NTOT * DDIM * 2);  // 32 KB
    float* simpos = sumexp + NTOT;                                    // 16 KB

    norm_kernel<<<B_ROWS / 4, 256, 0, stream>>>(zi, zj, zn, simpos, sumexp);
    sim_kernel<<<528 * 4, 256, 0, stream>>>(zn, sumexp);
    finalize_kernel<<<1, 256, 0, stream>>>(sumexp, simpos, out);
}

// Round 3
// 61.519 us; speedup vs baseline: 1.5609x; 1.5609x over previous
//
#include <hip/hip_runtime.h>
#include <hip/hip_bf16.h>
#include <math.h>

#define B_ROWS 4096
#define NTOT   8192
#define DDIM   256
#define CSCALE 1.6986436f      // sqrt(2*log2(e)); zn scaled so A.B = 2*log2(e)*cos
#define NPART  8

typedef __attribute__((ext_vector_type(8))) short  short8;   // 8 bf16
typedef __attribute__((ext_vector_type(4))) float  f32x4;

static __device__ inline unsigned short f2bf(float x) {
    union { float f; unsigned u; } v; v.f = x;
    unsigned r = v.u + 0x7fffu + ((v.u >> 16) & 1u);  // RNE
    return (unsigned short)(r >> 16);
}

// ---- kernel 1: fused normalize (scaled bf16) + positive-pair sims + partials zeroing ----
__global__ __launch_bounds__(256) void norm_kernel(
        const float* __restrict__ zi, const float* __restrict__ zj,
        unsigned short* __restrict__ zn, float* __restrict__ simpos,
        float* __restrict__ parts) {
    int pair = blockIdx.x * 4 + (threadIdx.x >> 6);
    int lane = threadIdx.x & 63;
    float4 vi = reinterpret_cast<const float4*>(zi + (size_t)pair * DDIM)[lane];
    float4 vj = reinterpret_cast<const float4*>(zj + (size_t)pair * DDIM)[lane];
    float ssi = vi.x*vi.x + vi.y*vi.y + vi.z*vi.z + vi.w*vi.w;
    float ssj = vj.x*vj.x + vj.y*vj.y + vj.z*vj.z + vj.w*vj.w;
    float dij = vi.x*vj.x + vi.y*vj.y + vi.z*vj.z + vi.w*vj.w;
    #pragma unroll
    for (int o = 32; o > 0; o >>= 1) {
        ssi += __shfl_xor(ssi, o);
        ssj += __shfl_xor(ssj, o);
        dij += __shfl_xor(dij, o);
    }
    float invi = 1.0f / fmaxf(sqrtf(ssi), 1e-8f);
    float invj = 1.0f / fmaxf(sqrtf(ssj), 1e-8f);
    float si = CSCALE * invi, sj = CSCALE * invj;
    ushort4 hi4, hj4;
    hi4.x = f2bf(vi.x * si); hi4.y = f2bf(vi.y * si);
    hi4.z = f2bf(vi.z * si); hi4.w = f2bf(vi.w * si);
    hj4.x = f2bf(vj.x * sj); hj4.y = f2bf(vj.y * sj);
    hj4.z = f2bf(vj.z * sj); hj4.w = f2bf(vj.w * sj);
    *reinterpret_cast<ushort4*>(zn + (size_t)pair * DDIM + lane * 4) = hi4;
    *reinterpret_cast<ushort4*>(zn + (size_t)(pair + B_ROWS) * DDIM + lane * 4) = hj4;
    if (lane == 0) simpos[pair] = 2.0f * dij * invi * invj;   // logits = cos/tau
    // zero the 8 partial-sum buffers (8*8192 floats over 1024 blocks)
    if (blockIdx.x < 256) parts[blockIdx.x * 256 + threadIdx.x] = 0.0f;
}

// ---- kernel 2: triangular fused sim + exp2 + row/col exp-sums ----
// 544 blocks: (ti,tj) with 128-row strip ti (64 strips), 512-col tile tj >= ti/4.
// Per block: 4 waves x 32 resident A-rows; loop over 64-col LDS-staged subtiles
// starting at the diagonal. Row sums in regs, col sums in LDS, one flush each.
__global__ __launch_bounds__(256, 2) void sim_kernel(
        const unsigned short* __restrict__ zn, float* __restrict__ parts) {
    __shared__ __align__(16) unsigned char tile[64 * 512];   // 32 KB
    __shared__ float csum_lds[4][512];                       // 8 KB

    // decode blockIdx -> (ti, tj): strip ti has 16 - (ti>>2) col tiles
    int rem = blockIdx.x, ti = 0;
    while (rem >= 16 - (ti >> 2)) { rem -= 16 - (ti >> 2); ++ti; }
    int tj = (ti >> 2) + rem;

    int wid  = threadIdx.x >> 6;
    int lane = threadIdx.x & 63;
    int l15  = lane & 15;
    int l4   = lane >> 4;
    int blockRow = ti * 128;
    int waveRow  = blockRow + wid * 32;
    int colT     = tj * 512;
    int d        = blockRow - colT;                  // multiple of 128
    int itStart  = (d > 0) ? (d >> 6) : 0;           // skip fully-below subtiles
    float* part  = parts + (size_t)(blockIdx.x & (NPART - 1)) * NTOT;

    // A fragments: 32 rows per wave resident (64 VGPRs)
    short8 a[2][8];
    #pragma unroll
    for (int rs = 0; rs < 2; ++rs) {
        const unsigned short* ap = zn + (size_t)(waveRow + rs * 16 + l15) * DDIM;
        #pragma unroll
        for (int c = 0; c < 8; ++c)
            a[rs][c] = *reinterpret_cast<const short8*>(ap + c * 32 + l4 * 8);
    }

    float rsum[2][4] = {{0,0,0,0},{0,0,0,0}};

    for (int it = itStart; it < 8; ++it) {
        int c0 = colT + it * 64;
        __syncthreads();   // protect LDS before overwrite
        #pragma unroll
        for (int p = 0; p < 8; ++p) {
            int id = p * 256 + threadIdx.x;
            int tr = id >> 5, ck = id & 31;
            uint4 v = *reinterpret_cast<const uint4*>(
                zn + (size_t)(c0 + tr) * DDIM + ck * 8);
            int off = tr * 512 + ((ck * 16) ^ ((tr & 7) << 4));
            *reinterpret_cast<uint4*>(tile + off) = v;
        }
        __syncthreads();

        bool crossing = (it * 64 < d + 128);   // subtile straddles the diagonal

        #pragma unroll
        for (int sub = 0; sub < 4; ++sub) {
            short8 b[8];
            int trr = sub * 16 + l15;
            int rowoff = trr * 512, swz = (trr & 7) << 4;
            #pragma unroll
            for (int c = 0; c < 8; ++c)
                b[c] = *reinterpret_cast<const short8*>(tile + rowoff + ((c * 64 + l4 * 16) ^ swz));
            int gcol = c0 + sub * 16 + l15;
            float cs = 0.0f;
            #pragma unroll
            for (int rs = 0; rs < 2; ++rs) {
                f32x4 acc = {0.f, 0.f, 0.f, 0.f};
                #pragma unroll
                for (int c = 0; c < 8; ++c)
                    acc = __builtin_amdgcn_mfma_f32_16x16x32_bf16(a[rs][c], b[c], acc, 0, 0, 0);
                #pragma unroll
                for (int j = 0; j < 4; ++j) {
                    float e = exp2f(acc[j]);             // zn pre-scaled
                    if (crossing) {
                        int grow = waveRow + rs * 16 + l4 * 4 + j;
                        e = (gcol > grow) ? e : 0.0f;    // strict upper triangle
                    }
                    rsum[rs][j] += e;
                    cs += e;
                }
            }
            // column sum: reduce the 4 row-groups (lanes differing in l4)
            cs += __shfl_xor(cs, 16);
            cs += __shfl_xor(cs, 32);
            if (l4 == 0) csum_lds[wid][it * 64 + sub * 16 + l15] = cs;
        }
    }

    // ---- flush rows: reduce across 16 col-lanes, one atomic per row ----
    #pragma unroll
    for (int rs = 0; rs < 2; ++rs)
        #pragma unroll
        for (int j = 0; j < 4; ++j) {
            float s = rsum[rs][j];
            #pragma unroll
            for (int m = 8; m >= 1; m >>= 1) s += __shfl_xor(s, m);
            rsum[rs][j] = s;
        }
    if (l15 == 0) {
        #pragma unroll
        for (int rs = 0; rs < 2; ++rs)
            #pragma unroll
            for (int j = 0; j < 4; ++j)
                atomicAdd(&part[waveRow + rs * 16 + l4 * 4 + j], rsum[rs][j]);
    }
    // ---- flush cols: sum the 4 per-wave LDS slices, one atomic per col ----
    __syncthreads();
    for (int c = itStart * 64 + threadIdx.x; c < 512; c += 256) {
        float s = csum_lds[0][c] + csum_lds[1][c] + csum_lds[2][c] + csum_lds[3][c];
        atomicAdd(&part[colT + c], s);
    }
}

// ---- kernel 3: loss = sum_r (log(sum_p parts[p][r]) - simpos[r % B]) / N ----
__global__ __launch_bounds__(1024) void finalize_kernel(
        const float* __restrict__ parts, const float* __restrict__ simpos,
        float* __restrict__ out) {
    __shared__ float red[16];
    int tid = threadIdx.x;
    float acc = 0.0f;
    for (int r = tid; r < NTOT; r += 1024) {
        float s = 0.0f;
        #pragma unroll
        for (int p = 0; p < NPART; ++p) s += parts[p * NTOT + r];
        acc += logf(s) - simpos[r & (B_ROWS - 1)];
    }
    #pragma unroll
    for (int o = 32; o > 0; o >>= 1) acc += __shfl_xor(acc, o);
    if ((tid & 63) == 0) red[tid >> 6] = acc;
    __syncthreads();
    if (tid == 0) {
        float t = 0.0f;
        #pragma unroll
        for (int w = 0; w < 16; ++w) t += red[w];
        out[0] = t / (float)NTOT;
    }
}

extern "C" void kernel_launch(void* const* d_in, const int* in_sizes, int n_in,
                              void* d_out, int out_size, void* d_ws, size_t ws_size,
                              hipStream_t stream) {
    const float* zi = (const float*)d_in[0];
    const float* zj = (const float*)d_in[1];
    float* out = (float*)d_out;

    unsigned short* zn = (unsigned short*)d_ws;                        // 4 MB
    float* parts  = (float*)((char*)d_ws + (size_t)NTOT * DDIM * 2);   // 256 KB
    float* simpos = parts + NPART * NTOT;                              // 16 KB

    norm_kernel<<<B_ROWS / 4, 256, 0, stream>>>(zi, zj, zn, simpos, parts);
    sim_kernel<<<544, 256, 0, stream>>>(zn, parts);
    finalize_kernel<<<1, 1024, 0, stream>>>(parts, simpos, out);
}